// Round 6
// baseline (401.335 us; speedup 1.0000x reference)
//
#include <hip/hip_runtime.h>
#include <hip/hip_bf16.h>

// ---------------------------------------------------------------------------
// SCFA fused pipeline, bf16 MFMA GEMMs, fp32 epilogues.
// B=8, C=256, N=4096, NH=4, HD=64.
// R10: spart/pout reverted to R7 dbuf+counted-vmcnt (R9 single-buf regressed
//   them); qkv upgraded to 256n x 128o tile, single 48KB buffer, 64 MFMA per
//   wave per K-step (2x fewer blocks/barriers/epilogues at same residency).
// ---------------------------------------------------------------------------

#define NPIX 4096

typedef __attribute__((ext_vector_type(8))) short bfrag;   // 8 bf16 (4 VGPR)
typedef __attribute__((ext_vector_type(4))) float f4acc;   // 4 fp32 acc

#define GLDS16(g, l) __builtin_amdgcn_global_load_lds( \
    (const __attribute__((address_space(1))) unsigned int*)(g), \
    (__attribute__((address_space(3))) unsigned int*)(l), 16, 0, 0)

__device__ __forceinline__ float bf2f(unsigned short h) {
  return __uint_as_float(((unsigned)h) << 16);
}
__device__ __forceinline__ unsigned short f2bf(float f) {
  unsigned u = __float_as_uint(f);
  unsigned r = (u + 0x7FFFu + ((u >> 16) & 1u)) >> 16;
  return (unsigned short)r;
}
// tanh-form gelu == x * sigmoid(1.5957691x + 0.07135481x^3); max err ~3e-3
__device__ __forceinline__ float gelu_f(float x) {
  float z = x * (1.5957691216f + 0.0713548163f * x * x);
  return x / (1.0f + __expf(-z));
}

// ---- prep: fold depthwise kernels, fold BN+bias ----------------------------
__global__ __launch_bounds__(256) void prep_kernel(
    const float* __restrict__ w3, const float* __restrict__ b3,
    const float* __restrict__ w5, const float* __restrict__ b5,
    const float* __restrict__ w7, const float* __restrict__ b7,
    const float* __restrict__ qb1, const float* __restrict__ g1,
    const float* __restrict__ be1, const float* __restrict__ m1,
    const float* __restrict__ v1,
    const float* __restrict__ qb2, const float* __restrict__ g2,
    const float* __restrict__ be2, const float* __restrict__ m2,
    const float* __restrict__ v2,
    float* __restrict__ weff, float* __restrict__ beff,
    float* __restrict__ alpha, float* __restrict__ beta)
{
  const int c = threadIdx.x;
  for (int ky = 0; ky < 7; ++ky)
    for (int kx = 0; kx < 7; ++kx) {
      float w = w7[c * 49 + ky * 7 + kx];
      if (ky >= 1 && ky <= 5 && kx >= 1 && kx <= 5)
        w += w5[c * 25 + (ky - 1) * 5 + (kx - 1)];
      if (ky >= 2 && ky <= 4 && kx >= 2 && kx <= 4)
        w += w3[c * 9 + (ky - 2) * 3 + (kx - 2)];
      weff[c * 49 + ky * 7 + kx] = w * (1.0f / 3.0f);
    }
  beff[c] = (b3[c] + b5[c] + b7[c]) * (1.0f / 3.0f);
  for (int o = c; o < 768; o += 256) {
    float inv1 = g1[o] / sqrtf(v1[o] + 1e-5f);
    alpha[o] = inv1;
    beta[o]  = qb1[o] * inv1 + be1[o] - m1[o] * inv1;
    float inv2 = g2[o] / sqrtf(v2[o] + 1e-5f);
    alpha[768 + o] = inv2;
    beta[768 + o]  = qb2[o] * inv2 + be2[o] - m2[o] * inv2;
  }
}

// ---- convert qkv weights fp32 -> bf16 (both streams) -----------------------
__global__ __launch_bounds__(256) void convert_w(
    const float* __restrict__ s1, const float* __restrict__ s2,
    unsigned short* __restrict__ d1, unsigned short* __restrict__ d2)
{
  int idx = blockIdx.x * 256 + threadIdx.x;
  d1[idx] = f2bf(s1[idx]);
  d2[idx] = f2bf(s2[idx]);
}

// ---- fused multi-scale depthwise conv -> bf16 [c][n], both streams ---------
// One block per (stream,b,c) plane. Row-shifted LDS layout: base(row) =
// 84*row + 8*((row>>3)&1) -> wave's 4 rows hit banks {0,8,16,24}, 2-way max.
__global__ __launch_bounds__(256) void ms_conv(
    const float* __restrict__ x1, const float* __restrict__ x2,
    const float* __restrict__ weff, const float* __restrict__ beff,
    unsigned short* __restrict__ xf0, unsigned short* __restrict__ xf1)
{
  __shared__ float tile[5888];
  const int bc2 = blockIdx.x;                   // [stream][b][c]
  const int s = bc2 >> 11, bc = bc2 & 2047;
  const int c = bc & 255;
  const int tid = threadIdx.x;
  const float* src = (s ? x2 : x1) + (size_t)bc * NPIX;
  float wreg[49];
#pragma unroll
  for (int i = 0; i < 49; ++i) wreg[i] = weff[c * 49 + i];
  const float bias = beff[c];
  // ---- stage interior: 64 rows x 16 quads, linear global read -------------
  float4 vv[4];
#pragma unroll
  for (int k = 0; k < 4; ++k)
    vv[k] = *(const float4*)&src[(k * 256 + tid) * 4];
#pragma unroll
  for (int k = 0; k < 4; ++k) {
    const int idx = k * 256 + tid;
    const int row = (idx >> 4) + 3;           // tile rows 3..66
    const int col = 4 + (idx & 15) * 4;       // tile cols 4..67
    *(float4*)&tile[84 * row + ((row >> 3) & 1) * 8 + col] = vv[k];
  }
  // ---- zero pads ----------------------------------------------------------
  const float4 zq = {0.0f, 0.0f, 0.0f, 0.0f};
  for (int idx = tid; idx < 306; idx += 256) {
    int row, col;
    if (idx < 114) {
      int r6 = idx / 19;
      col = (idx - r6 * 19) * 4;
      row = (r6 < 3) ? r6 : (r6 + 64);        // rows 0..2, 67..69
    } else {
      int j = idx - 114;
      int r64 = j / 3, q = j - r64 * 3;
      row = 3 + r64;                           // rows 3..66
      col = (q == 0) ? 0 : (64 + q * 4);       // cols 0, 68, 72
    }
    *(float4*)&tile[84 * row + ((row >> 3) & 1) * 8 + col] = zq;
  }
  __syncthreads();
  // ---- compute: 4x4 outputs per thread ------------------------------------
  const int x0 = (tid & 15) * 4;
  const int y0 = (tid >> 4) * 4;
  float acc[4][4];
#pragma unroll
  for (int yo = 0; yo < 4; ++yo)
#pragma unroll
    for (int xo = 0; xo < 4; ++xo) acc[yo][xo] = bias;
#pragma unroll
  for (int r = 0; r < 10; ++r) {
    const int row = y0 + r;
    const int rb = 84 * row + ((row >> 3) & 1) * 8 + x0;
    float seg[12];
    *(float4*)&seg[0] = *(const float4*)&tile[rb];
    *(float4*)&seg[4] = *(const float4*)&tile[rb + 4];
    *(float4*)&seg[8] = *(const float4*)&tile[rb + 8];
    const int yolo = (r >= 6) ? (r - 6) : 0;
    const int yohi = (r < 3) ? r : 3;
#pragma unroll
    for (int yo = 0; yo < 4; ++yo) {
      if (yo < yolo || yo > yohi) continue;
      const int ky = r - yo;
#pragma unroll
      for (int kx = 0; kx < 7; ++kx) {
        const float w = wreg[ky * 7 + kx];
#pragma unroll
        for (int xo = 0; xo < 4; ++xo)
          acc[yo][xo] = fmaf(w, seg[1 + xo + kx], acc[yo][xo]);
      }
    }
  }
  unsigned short* dst = (s ? xf1 : xf0) + (size_t)bc * NPIX;
#pragma unroll
  for (int yo = 0; yo < 4; ++yo) {
    ushort4 u;
    u.x = f2bf(acc[yo][0]); u.y = f2bf(acc[yo][1]);
    u.z = f2bf(acc[yo][2]); u.w = f2bf(acc[yo][3]);
    *(ushort4*)&dst[(y0 + yo) * 64 + x0] = u;
  }
}

// ---- bf16 [R rows][4096] -> [4096][256] tile transpose, both streams -------
__global__ __launch_bounds__(256) void transpose_bf16(
    const unsigned short* __restrict__ s0, unsigned short* __restrict__ d0,
    const unsigned short* __restrict__ s1, unsigned short* __restrict__ d1,
    long sb, long db)
{
  __shared__ unsigned short T[64][72];
  const int n0 = blockIdx.x * 64, c0 = blockIdx.y * 64;
  const int z = blockIdx.z, st = z >> 3, b = z & 7;
  const unsigned short* src = st ? s1 : s0;
  unsigned short* dst = st ? d1 : d0;
  const int t = threadIdx.x;
  const int rhi = t >> 4, c4 = (t & 15) * 4;
#pragma unroll
  for (int rr = 0; rr < 4; ++rr) {
    int row = rr * 16 + rhi;
    ushort4 u = *(const ushort4*)&src[(size_t)b * sb + (size_t)(c0 + row) * NPIX + n0 + c4];
    T[row][c4 + 0] = u.x; T[row][c4 + 1] = u.y;
    T[row][c4 + 2] = u.z; T[row][c4 + 3] = u.w;
  }
  __syncthreads();
#pragma unroll
  for (int rr = 0; rr < 4; ++rr) {
    int nrow = rr * 16 + rhi;
    ushort4 u;
    u.x = T[c4 + 0][nrow]; u.y = T[c4 + 1][nrow];
    u.z = T[c4 + 2][nrow]; u.w = T[c4 + 3][nrow];
    *(ushort4*)&dst[(size_t)b * db + (size_t)(n0 + nrow) * 256 + c0 + c4] = u;
  }
}

// ---- qkv 1x1 GEMM (MFMA), 256n x 128o tile, single 48KB LDS buffer ---------
// D[n][o], A=Xt(n rows), B=W(o rows). LDS swizzle: slot g -> g ^ (row & 7).
// Per wave: 128n x 64o sub-tile -> acc[8][4], 64 MFMA per K-step.
// Epilogue: BN+gelu, ushort4 stores to qkv[o][n], fused q/k row-sumsq atomics.
__global__ __launch_bounds__(256) void qkv_gemm(
    const unsigned short* __restrict__ W1, const unsigned short* __restrict__ W2,
    const unsigned short* __restrict__ X0, const unsigned short* __restrict__ X1,
    const float* __restrict__ alpha, const float* __restrict__ beta,
    unsigned short* __restrict__ q1, unsigned short* __restrict__ q2,
    float* __restrict__ ns)
{
  __shared__ unsigned short As[128 * 64];  // W tile (o rows), 16KB
  __shared__ unsigned short Bs[256 * 64];  // Xt tile (n rows), 32KB
  const int n0 = blockIdx.x * 256, o0 = blockIdx.y * 128;
  const int z = blockIdx.z, s = z >> 3, b = z & 7;
  const unsigned short* Wb = s ? W2 : W1;
  const unsigned short* Xt = s ? X1 : X0;
  unsigned short* qkv = s ? q2 : q1;
  const float* al = alpha + s * 768;
  const float* be = beta + s * 768;
  float* normsq = ns + s * 4096;
  const int tid = threadIdx.x, w = tid >> 6, lane = tid & 63;
  const int wm = (w & 1) * 128;  // n wave offset
  const int wn = (w >> 1) * 64;  // o wave offset
  const int lrow8 = lane >> 3;
  const int lcolsw = ((lane & 7) ^ lrow8) * 8;  // swizzled source column
  const int fslot = lane & 7;                    // read-side row&7
  f4acc acc[8][4] = {};
  auto stage = [&](int kc) {
#pragma unroll
    for (int j = 0; j < 4; ++j) {
      int i = w * 4 + j;
      GLDS16(Wb + (size_t)(o0 + i * 8 + lrow8) * 256 + kc + lcolsw, &As[i * 512]);
    }
#pragma unroll
    for (int j = 0; j < 8; ++j) {
      int i = w * 8 + j;
      GLDS16(Xt + (size_t)b * 1048576 + (size_t)(n0 + i * 8 + lrow8) * 256 + kc + lcolsw,
             &Bs[i * 512]);
    }
  };
  stage(0);
#pragma unroll
  for (int t = 0; t < 4; ++t) {
    __syncthreads();   // own vmcnt drained + whole block's stage visible
#pragma unroll
    for (int ks = 0; ks < 2; ++ks) {
      const int slot = ((ks * 4 + (lane >> 4)) ^ fslot) * 8;
      bfrag a[8], bb[4];
#pragma unroll
      for (int mt = 0; mt < 8; ++mt)   // A = Xt rows (n)
        a[mt] = *(const bfrag*)&Bs[(wm + mt * 16 + (lane & 15)) * 64 + slot];
#pragma unroll
      for (int nt = 0; nt < 4; ++nt)   // B = W rows (o)
        bb[nt] = *(const bfrag*)&As[(wn + nt * 16 + (lane & 15)) * 64 + slot];
#pragma unroll
      for (int mt = 0; mt < 8; ++mt)
#pragma unroll
        for (int nt = 0; nt < 4; ++nt)
          acc[mt][nt] = __builtin_amdgcn_mfma_f32_16x16x32_bf16(a[mt], bb[nt], acc[mt][nt], 0, 0, 0);
    }
    if (t < 3) {
      __syncthreads();   // all reads of this tile done before overwrite
      stage((t + 1) * 64);
    }
  }
  // epilogue: D rows = n (regs), cols = o (lane&15)
#pragma unroll
  for (int nt = 0; nt < 4; ++nt) {
    const int o = o0 + wn + nt * 16 + (lane & 15);
    const float alv = al[o], bev = be[o];
    unsigned short* orow = qkv + ((size_t)b * 768 + o) * NPIX;
    float sq = 0.0f;
#pragma unroll
    for (int mt = 0; mt < 8; ++mt) {
      const int n = n0 + wm + mt * 16 + (lane >> 4) * 4;
      float v0 = gelu_f(acc[mt][nt][0] * alv + bev);
      float v1 = gelu_f(acc[mt][nt][1] * alv + bev);
      float v2 = gelu_f(acc[mt][nt][2] * alv + bev);
      float v3 = gelu_f(acc[mt][nt][3] * alv + bev);
      ushort4 u;
      u.x = f2bf(v0); u.y = f2bf(v1); u.z = f2bf(v2); u.w = f2bf(v3);
      *(ushort4*)&orow[n] = u;
      sq += v0 * v0 + v1 * v1 + v2 * v2 + v3 * v3;
    }
    if (o0 + wn + nt * 16 < 512) {  // q or k rows
      sq += __shfl_xor(sq, 16);
      sq += __shfl_xor(sq, 32);
      if (lane < 16) atomicAdd(&normsq[b * 512 + o], sq);
    }
  }
}

// ---- spart (MFMA), both streams, 2-phase dbuf pipeline (R7 form) -----------
// Sp[c][d] += sum_n q[c][n]*k[d][n]; A=k(d), B=q(c).
// grid (8 chunks of 512 n, 4 h, 16 = stream*8+b). 128-el rows, swizzle &15.
__global__ __launch_bounds__(256) void spart_kernel(
    const unsigned short* __restrict__ qkv1, const unsigned short* __restrict__ qkv2,
    float* __restrict__ Sp0, float* __restrict__ Sp1)
{
  __shared__ unsigned short Qs[2][64 * 128];
  __shared__ unsigned short Ks[2][64 * 128];
  const int ck = blockIdx.x, h = blockIdx.y;
  const int z = blockIdx.z, s = z >> 3, b = z & 7;
  const unsigned short* qs = s ? qkv2 : qkv1;
  const unsigned short* kp = (s ? qkv1 : qkv2) + 256 * NPIX;
  float* Sp = s ? Sp1 : Sp0;
  const int tid = threadIdx.x, w = tid >> 6, lane = tid & 63;
  const int lrow16 = lane >> 4;
  const size_t qbase = ((size_t)b * 768 + h * 64) * NPIX;
  f4acc acc[4] = {};   // mt over d tiles
  auto stage = [&](int buf, int it) {
    const int noff = ck * 512 + it * 128;
#pragma unroll
    for (int j = 0; j < 4; ++j) {
      int i = w * 4 + j;
      int row = i * 4 + lrow16;
      int colsw = ((lane & 15) ^ (row & 15)) * 8;
      GLDS16(qs + qbase + (size_t)row * NPIX + noff + colsw, &Qs[buf][i * 512]);
      GLDS16(kp + qbase + (size_t)row * NPIX + noff + colsw, &Ks[buf][i * 512]);
    }
  };
  stage(0, 0);
#pragma unroll
  for (int it = 0; it < 4; ++it) {
    const int cur = it & 1;
    if (it < 3) stage(cur ^ 1, it + 1);
    if (it < 3) asm volatile("s_waitcnt vmcnt(8)" ::: "memory");
    else        asm volatile("s_waitcnt vmcnt(0)" ::: "memory");
    __builtin_amdgcn_s_barrier();
#pragma unroll
    for (int kk = 0; kk < 4; ++kk) {
      const int slot = ((kk * 4 + (lane >> 4)) ^ (lane & 15)) * 8;
      bfrag bq = *(const bfrag*)&Qs[cur][(w * 16 + (lane & 15)) * 128 + slot];  // B = q (c)
#pragma unroll
      for (int mt = 0; mt < 4; ++mt) {
        bfrag ak = *(const bfrag*)&Ks[cur][(mt * 16 + (lane & 15)) * 128 + slot];  // A = k (d)
        acc[mt] = __builtin_amdgcn_mfma_f32_16x16x32_bf16(ak, bq, acc[mt], 0, 0, 0);
      }
    }
    __builtin_amdgcn_s_barrier();
  }
  // D rows = d (regs), cols = c (lane&15); c covered by wave w: w*16..+15
  float* dst = Sp + ((size_t)(ck * 32) + b * 4 + h) * 4096;
  const int c = w * 16 + (lane & 15);
#pragma unroll
  for (int mt = 0; mt < 4; ++mt)
    *(float4*)&dst[c * 64 + mt * 16 + (lane >> 4) * 4] = *(float4*)&acc[mt];
}

// ---- reduce partials, scale by inv norms * temp, softmax, write bf16 -------
__global__ __launch_bounds__(256) void softattn(
    const float* __restrict__ Sp0, const float* __restrict__ Sp1,
    const float* __restrict__ ns,
    unsigned short* __restrict__ at0, unsigned short* __restrict__ at1)
{
  const int bh2 = blockIdx.x;            // [stream][b][h]
  const int s = bh2 >> 5, bh = bh2 & 31;
  const int b = bh >> 2, h = bh & 3;
  const float* Sp = s ? Sp1 : Sp0;
  const float* nsq = ns + s * 4096;
  const float* nsk = ns + (s ^ 1) * 4096;
  unsigned short* attn = s ? at1 : at0;
  const int wv = threadIdx.x >> 6, lane = threadIdx.x & 63;
  const float ikd = 1.0f / fmaxf(sqrtf(nsk[b * 512 + 256 + h * 64 + lane]), 1e-12f);
  for (int c = wv; c < 64; c += 4) {
    float sm = 0.0f;
#pragma unroll
    for (int ch = 0; ch < 8; ++ch)
      sm += Sp[((size_t)(ch * 32) + bh) * 4096 + c * 64 + lane];
    const float iq = 1.0f / fmaxf(sqrtf(nsq[b * 512 + h * 64 + c]), 1e-12f);
    float zv = sm * 0.125f * iq * ikd;
    float m = zv;
#pragma unroll
    for (int off = 32; off > 0; off >>= 1) m = fmaxf(m, __shfl_xor(m, off));
    float e = expf(zv - m);
    float sum = e;
#pragma unroll
    for (int off = 32; off > 0; off >>= 1) sum += __shfl_xor(sum, off);
    attn[(size_t)bh * 4096 + c * 64 + lane] = f2bf(e / sum);
  }
}

// ---- av (MFMA), both streams: xout_t[n'][c] = sum_d attn[c][d]*v_t[n'][d] --
// A = attn (c rows), B = vt (n' rows) -> regs = 4 consecutive c at fixed n'.
// grid (16 chunks of 256 n', 4 h, 16 = stream*8+b).
__global__ __launch_bounds__(256) void av_kernel(
    const unsigned short* __restrict__ vt0, const unsigned short* __restrict__ vt1,
    const unsigned short* __restrict__ at0, const unsigned short* __restrict__ at1,
    unsigned short* __restrict__ xo0, unsigned short* __restrict__ xo1,
    long db, float* __restrict__ pool)
{
  __shared__ unsigned short Vs[256 * 64];
  __shared__ unsigned short At[64 * 64];
  const int n0 = blockIdx.x * 256, h = blockIdx.y;
  const int z = blockIdx.z, s = z >> 3, b = z & 7;
  const unsigned short* vt = s ? vt1 : vt0;
  const unsigned short* attn = s ? at1 : at0;
  unsigned short* xout = s ? xo1 : xo0;
  float* pl = pool + s * 2048;
  const int tid = threadIdx.x, w = tid >> 6, lane = tid & 63;
  const int lrow8 = lane >> 3;
  const int lcolsw = ((lane & 7) ^ lrow8) * 8;
  const int bh = b * 4 + h;
#pragma unroll
  for (int j = 0; j < 8; ++j) {
    int i = w * 8 + j;
    GLDS16(vt + ((size_t)b * 1048576 + (size_t)(n0 + i * 8 + lrow8) * 256) + h * 64 + lcolsw,
           &Vs[i * 512]);
  }
#pragma unroll
  for (int j = 0; j < 2; ++j) {
    int i = w * 2 + j;
    GLDS16(attn + (size_t)bh * 4096 + (size_t)(i * 8 + lrow8) * 64 + lcolsw, &At[i * 512]);
  }
  __syncthreads();
  f4acc acc[4][4] = {};   // [mt = c tile][nt = n' tile]
#pragma unroll
  for (int ks = 0; ks < 2; ++ks) {
    const int slot = ((ks * 4 + (lane >> 4)) ^ (lane & 7)) * 8;
    bfrag a[4], bb[4];
#pragma unroll
    for (int mt = 0; mt < 4; ++mt)    // A = attn rows (c)
      a[mt] = *(const bfrag*)&At[(mt * 16 + (lane & 15)) * 64 + slot];
#pragma unroll
    for (int nt = 0; nt < 4; ++nt)    // B = vt rows (n')
      bb[nt] = *(const bfrag*)&Vs[(w * 64 + nt * 16 + (lane & 15)) * 64 + slot];
#pragma unroll
    for (int mt = 0; mt < 4; ++mt)
#pragma unroll
      for (int nt = 0; nt < 4; ++nt)
        acc[mt][nt] = __builtin_amdgcn_mfma_f32_16x16x32_bf16(a[mt], bb[nt], acc[mt][nt], 0, 0, 0);
  }
  // D rows = c (regs), cols = n' (lane&15)
#pragma unroll
  for (int mt = 0; mt < 4; ++mt) {
    const int c = mt * 16 + (lane >> 4) * 4;
    float s0 = 0.0f, s1 = 0.0f, s2 = 0.0f, s3 = 0.0f;
#pragma unroll
    for (int nt = 0; nt < 4; ++nt) {
      const int np = n0 + w * 64 + nt * 16 + (lane & 15);
      ushort4 u;
      u.x = f2bf(acc[mt][nt][0]); u.y = f2bf(acc[mt][nt][1]);
      u.z = f2bf(acc[mt][nt][2]); u.w = f2bf(acc[mt][nt][3]);
      *(ushort4*)&xout[(size_t)b * db + (size_t)np * 256 + h * 64 + c] = u;
      s0 += acc[mt][nt][0]; s1 += acc[mt][nt][1];
      s2 += acc[mt][nt][2]; s3 += acc[mt][nt][3];
    }
    // reduce over n' (lane&15) for fixed c
    s0 += __shfl_xor(s0, 1); s0 += __shfl_xor(s0, 2); s0 += __shfl_xor(s0, 4); s0 += __shfl_xor(s0, 8);
    s1 += __shfl_xor(s1, 1); s1 += __shfl_xor(s1, 2); s1 += __shfl_xor(s1, 4); s1 += __shfl_xor(s1, 8);
    s2 += __shfl_xor(s2, 1); s2 += __shfl_xor(s2, 2); s2 += __shfl_xor(s2, 4); s2 += __shfl_xor(s2, 8);
    s3 += __shfl_xor(s3, 1); s3 += __shfl_xor(s3, 2); s3 += __shfl_xor(s3, 4); s3 += __shfl_xor(s3, 8);
    if ((lane & 15) == 0) {
      atomicAdd(&pl[b * 256 + h * 64 + c + 0], s0);
      atomicAdd(&pl[b * 256 + h * 64 + c + 1], s1);
      atomicAdd(&pl[b * 256 + h * 64 + c + 2], s2);
      atomicAdd(&pl[b * 256 + h * 64 + c + 3], s3);
    }
  }
}

// ---- SE gate MLP + fold gate into per-batch bf16 output-proj weights -------
__global__ __launch_bounds__(256) void segate_scale(
    const float* __restrict__ pool, const float* __restrict__ w1,
    const float* __restrict__ b1, const float* __restrict__ w2,
    const float* __restrict__ b2,
    const float* __restrict__ W1, const float* __restrict__ W2,
    unsigned short* __restrict__ Wg)
{
  const int b16 = blockIdx.x;   // [stream][b]
  const int tid = threadIdx.x;
  __shared__ float p[256];
  __shared__ float hh[32];
  p[tid] = pool[b16 * 256 + tid] * (1.0f / 4096.0f);
  __syncthreads();
  if (tid < 32) {
    float s = b1[tid];
    for (int c = 0; c < 256; ++c) s = fmaf(w1[tid * 256 + c], p[c], s);
    hh[tid] = fmaxf(s, 0.0f);
  }
  __syncthreads();
  float s = b2[tid];
#pragma unroll
  for (int r = 0; r < 32; ++r) s = fmaf(w2[tid * 32 + r], hh[r], s);
  const float g = 1.0f / (1.0f + expf(-s));
  const float* W = (b16 >> 3) ? W2 : W1;
  for (int o = 0; o < 256; ++o)
    Wg[(size_t)b16 * 65536 + o * 256 + tid] = f2bf(W[o * 256 + tid] * g);
}

// ---- pout (MFMA), both streams, 2-phase dbuf pipeline (R7 form) ------------
// out[o][n] = sum_c Wg[o][c]*xout_t[n][c] + bias + res.
__global__ __launch_bounds__(256) void pout_gemm(
    const unsigned short* __restrict__ Wgall,
    const unsigned short* __restrict__ X0, const unsigned short* __restrict__ X1,
    long db, const float* __restrict__ bias0, const float* __restrict__ bias1,
    const float* __restrict__ xr0, const float* __restrict__ xr1,
    float* __restrict__ out)
{
  __shared__ unsigned short As[2][128 * 64];  // Wg (o rows)
  __shared__ unsigned short Bs[2][128 * 64];  // Xt (n rows)
  const int n0 = blockIdx.x * 128, o0 = blockIdx.y * 128;
  const int z = blockIdx.z, s = z >> 3, b = z & 7;
  const unsigned short* Wg = Wgall + (size_t)z * 65536;
  const unsigned short* Xt = s ? X1 : X0;
  const float* bias = s ? bias1 : bias0;
  const float* xresb = s ? xr1 : xr0;
  float* outb = out + (size_t)s * 8388608;
  const int tid = threadIdx.x, w = tid >> 6, lane = tid & 63;
  const int wm = (w & 1) * 64;   // n
  const int wn = (w >> 1) * 64;  // o
  const int lrow8 = lane >> 3;
  const int lcolsw = ((lane & 7) ^ lrow8) * 8;
  const int fslot = lane & 7;
  f4acc acc[4][4] = {};
  auto stage = [&](int buf, int kc) {
#pragma unroll
    for (int j = 0; j < 4; ++j) {
      int i = w * 4 + j;
      GLDS16(Wg + (size_t)(o0 + i * 8 + lrow8) * 256 + kc + lcolsw, &As[buf][i * 512]);
      GLDS16(Xt + (size_t)b * db + (size_t)(n0 + i * 8 + lrow8) * 256 + kc + lcolsw,
             &Bs[buf][i * 512]);
    }
  };
  stage(0, 0);
#pragma unroll
  for (int t = 0; t < 4; ++t) {
    const int cur = t & 1;
    if (t < 3) stage(cur ^ 1, (t + 1) * 64);
    if (t < 3) asm volatile("s_waitcnt vmcnt(8)" ::: "memory");
    else       asm volatile("s_waitcnt vmcnt(0)" ::: "memory");
    __builtin_amdgcn_s_barrier();
#pragma unroll
    for (int ks = 0; ks < 2; ++ks) {
      const int slot = ((ks * 4 + (lane >> 4)) ^ fslot) * 8;
      bfrag a[4], bb[4];
#pragma unroll
      for (int mt = 0; mt < 4; ++mt)   // A = Xt rows (n)
        a[mt] = *(const bfrag*)&Bs[cur][(wm + mt * 16 + (lane & 15)) * 64 + slot];
#pragma unroll
      for (int nt = 0; nt < 4; ++nt)   // B = Wg rows (o)
        bb[nt] = *(const bfrag*)&As[cur][(wn + nt * 16 + (lane & 15)) * 64 + slot];
#pragma unroll
      for (int mt = 0; mt < 4; ++mt)
#pragma unroll
        for (int nt = 0; nt < 4; ++nt)
          acc[mt][nt] = __builtin_amdgcn_mfma_f32_16x16x32_bf16(a[mt], bb[nt], acc[mt][nt], 0, 0, 0);
    }
    __builtin_amdgcn_s_barrier();
  }
#pragma unroll
  for (int nt = 0; nt < 4; ++nt) {
    const int o = o0 + wn + nt * 16 + (lane & 15);
    const float bi = bias[o];
    const float* res = xresb + ((size_t)b * 256 + o) * NPIX;
    float* orow = outb + ((size_t)b * 256 + o) * NPIX;
#pragma unroll
    for (int mt = 0; mt < 4; ++mt) {
      const int n = n0 + wm + mt * 16 + (lane >> 4) * 4;
      float4 r4 = *(const float4*)&res[n];
      float4 ov;
      ov.x = acc[mt][nt][0] + bi + r4.x;
      ov.y = acc[mt][nt][1] + bi + r4.y;
      ov.z = acc[mt][nt][2] + bi + r4.z;
      ov.w = acc[mt][nt][3] + bi + r4.w;
      *(float4*)&orow[n] = ov;
    }
  }
}

extern "C" void kernel_launch(void* const* d_in, const int* in_sizes, int n_in,
                              void* d_out, int out_size, void* d_ws, size_t ws_size,
                              hipStream_t stream) {
  const float* x1    = (const float*)d_in[0];
  const float* x2    = (const float*)d_in[1];
  const float* ms_w3 = (const float*)d_in[2];
  const float* ms_b3 = (const float*)d_in[3];
  const float* ms_w5 = (const float*)d_in[4];
  const float* ms_b5 = (const float*)d_in[5];
  const float* ms_w7 = (const float*)d_in[6];
  const float* ms_b7 = (const float*)d_in[7];
  const float* qkv1_w = (const float*)d_in[8];
  const float* qkv1_b = (const float*)d_in[9];
  const float* bn1_g = (const float*)d_in[10];
  const float* bn1_b = (const float*)d_in[11];
  const float* bn1_m = (const float*)d_in[12];
  const float* bn1_v = (const float*)d_in[13];
  const float* qkv2_w = (const float*)d_in[14];
  const float* qkv2_b = (const float*)d_in[15];
  const float* bn2_g = (const float*)d_in[16];
  const float* bn2_b = (const float*)d_in[17];
  const float* bn2_m = (const float*)d_in[18];
  const float* bn2_v = (const float*)d_in[19];
  const float* ca_w1 = (const float*)d_in[20];
  const float* ca_b1 = (const float*)d_in[21];
  const float* ca_w2 = (const float*)d_in[22];
  const float* ca_b2 = (const float*)d_in[23];
  const float* po1_w = (const float*)d_in[24];
  const float* po1_b = (const float*)d_in[25];
  const float* po2_w = (const float*)d_in[26];
  const float* po2_b = (const float*)d_in[27];

  char* ws = (char*)d_ws;
  float* weff  = (float*)(ws + 0);
  float* beff  = (float*)(ws + 51200);
  float* alpha = (float*)(ws + 53248);
  float* beta  = (float*)(ws + 59392);
  float* normsq = (float*)(ws + 65536);    // 2 streams x 8*512 fp32
  float* pool  = (float*)(ws + 98304);     // 2 streams x 2048 fp32
  unsigned short* W1b = (unsigned short*)(ws + 131072);
  unsigned short* W2b = (unsigned short*)(ws + 524288);
  unsigned short* Wg  = (unsigned short*)(ws + 917504);   // 16 x 65536 bf16
  unsigned short* attn1 = (unsigned short*)(ws + 3014656);
  unsigned short* attn2 = (unsigned short*)(ws + 3276800);
  float* Sp    = (float*)(ws + 3538944);   // stream1 partials, 4.2 MB
  unsigned short* xf   = (unsigned short*)(ws + 7733248);   // [b][256][4096]
  unsigned short* xf_t = (unsigned short*)(ws + 24510464);  // [b][4096][256]
  unsigned short* qkv1 = (unsigned short*)(ws + 41287680);  // [b][768][4096]
  unsigned short* qkv2 = (unsigned short*)(ws + 91619328);
  // stream-2 early-stage scratch lives in d_out (dead until pout_gemm)
  unsigned short* xf2   = (unsigned short*)d_out;
  unsigned short* xf2_t = (unsigned short*)((char*)d_out + 16777216);
  // stream-2 score partials live in the (dead at that point) xf region
  float* Sp2 = (float*)(ws + 7733248);
  unsigned short* v1t   = xf;
  unsigned short* v2t   = xf_t;
  unsigned short* xout1 = qkv2;   // per-batch [n][256] in dead q/k chunks
  unsigned short* xout2 = qkv1;
  const long QKV_BSTR = 768L * 4096;

  float* outf = (float*)d_out;

  prep_kernel<<<1, 256, 0, stream>>>(ms_w3, ms_b3, ms_w5, ms_b5, ms_w7, ms_b7,
                                     qkv1_b, bn1_g, bn1_b, bn1_m, bn1_v,
                                     qkv2_b, bn2_g, bn2_b, bn2_m, bn2_v,
                                     weff, beff, alpha, beta);
  convert_w<<<768, 256, 0, stream>>>(qkv1_w, qkv2_w, W1b, W2b);
  hipMemsetAsync(ws + 65536, 0, 49152, stream);  // normsq(both) + pool(both)

  ms_conv<<<4096, 256, 0, stream>>>(x1, x2, weff, beff, xf, xf2);
  transpose_bf16<<<dim3(64, 4, 16), 256, 0, stream>>>(xf, xf_t, xf2, xf2_t,
                                                      1048576L, 1048576L);
  qkv_gemm<<<dim3(16, 6, 16), 256, 0, stream>>>(W1b, W2b, xf_t, xf2_t,
                                                alpha, beta, qkv1, qkv2, normsq);

  spart_kernel<<<dim3(8, 4, 16), 256, 0, stream>>>(qkv1, qkv2, Sp, Sp2);
  softattn<<<64, 256, 0, stream>>>(Sp, Sp2, normsq, attn1, attn2);

  transpose_bf16<<<dim3(64, 4, 16), 256, 0, stream>>>(qkv1 + 512 * NPIX, v1t,
                                                      qkv2 + 512 * NPIX, v2t,
                                                      3145728L, 1048576L);

  av_kernel<<<dim3(16, 4, 16), 256, 0, stream>>>(v1t, v2t, attn1, attn2,
                                                 xout1, xout2, QKV_BSTR, pool);

  segate_scale<<<16, 256, 0, stream>>>(pool, ca_w1, ca_b1, ca_w2, ca_b2,
                                       po1_w, po2_w, Wg);

  pout_gemm<<<dim3(32, 2, 16), 256, 0, stream>>>(Wg, xout1, xout2, QKV_BSTR,
                                                 po1_b, po2_b, x1, x2, outf);
}

// Round 7
// 371.987 us; speedup vs baseline: 1.0789x; 1.0789x over previous
//
#include <hip/hip_runtime.h>
#include <hip/hip_bf16.h>

// ---------------------------------------------------------------------------
// SCFA fused pipeline, bf16 MFMA GEMMs, fp32 epilogues.
// B=8, C=256, N=4096, NH=4, HD=64.
// R11: qkv back to R9 form (128x128, single 32KB buffer -- measured 62us);
//   v-blocks transpose their output tile through the dead staging LDS and
//   write vt[n][c] directly -> transpose2 dispatch deleted. gelu uses
//   v_rcp_f32. spart/pout stay R7-dbuf (measured best).
// ---------------------------------------------------------------------------

#define NPIX 4096

typedef __attribute__((ext_vector_type(8))) short bfrag;   // 8 bf16 (4 VGPR)
typedef __attribute__((ext_vector_type(4))) float f4acc;   // 4 fp32 acc

#define GLDS16(g, l) __builtin_amdgcn_global_load_lds( \
    (const __attribute__((address_space(1))) unsigned int*)(g), \
    (__attribute__((address_space(3))) unsigned int*)(l), 16, 0, 0)

__device__ __forceinline__ float bf2f(unsigned short h) {
  return __uint_as_float(((unsigned)h) << 16);
}
__device__ __forceinline__ unsigned short f2bf(float f) {
  unsigned u = __float_as_uint(f);
  unsigned r = (u + 0x7FFFu + ((u >> 16) & 1u)) >> 16;
  return (unsigned short)r;
}
// tanh-form gelu == x * sigmoid(1.5957691x + 0.07135481x^3); max err ~3e-3
__device__ __forceinline__ float gelu_f(float x) {
  float z = x * (1.5957691216f + 0.0713548163f * x * x);
  return x * __builtin_amdgcn_rcpf(1.0f + __expf(-z));
}

// ---- prep: fold depthwise kernels, fold BN+bias ----------------------------
__global__ __launch_bounds__(256) void prep_kernel(
    const float* __restrict__ w3, const float* __restrict__ b3,
    const float* __restrict__ w5, const float* __restrict__ b5,
    const float* __restrict__ w7, const float* __restrict__ b7,
    const float* __restrict__ qb1, const float* __restrict__ g1,
    const float* __restrict__ be1, const float* __restrict__ m1,
    const float* __restrict__ v1,
    const float* __restrict__ qb2, const float* __restrict__ g2,
    const float* __restrict__ be2, const float* __restrict__ m2,
    const float* __restrict__ v2,
    float* __restrict__ weff, float* __restrict__ beff,
    float* __restrict__ alpha, float* __restrict__ beta)
{
  const int c = threadIdx.x;
  for (int ky = 0; ky < 7; ++ky)
    for (int kx = 0; kx < 7; ++kx) {
      float w = w7[c * 49 + ky * 7 + kx];
      if (ky >= 1 && ky <= 5 && kx >= 1 && kx <= 5)
        w += w5[c * 25 + (ky - 1) * 5 + (kx - 1)];
      if (ky >= 2 && ky <= 4 && kx >= 2 && kx <= 4)
        w += w3[c * 9 + (ky - 2) * 3 + (kx - 2)];
      weff[c * 49 + ky * 7 + kx] = w * (1.0f / 3.0f);
    }
  beff[c] = (b3[c] + b5[c] + b7[c]) * (1.0f / 3.0f);
  for (int o = c; o < 768; o += 256) {
    float inv1 = g1[o] / sqrtf(v1[o] + 1e-5f);
    alpha[o] = inv1;
    beta[o]  = qb1[o] * inv1 + be1[o] - m1[o] * inv1;
    float inv2 = g2[o] / sqrtf(v2[o] + 1e-5f);
    alpha[768 + o] = inv2;
    beta[768 + o]  = qb2[o] * inv2 + be2[o] - m2[o] * inv2;
  }
}

// ---- convert qkv weights fp32 -> bf16 (both streams) -----------------------
__global__ __launch_bounds__(256) void convert_w(
    const float* __restrict__ s1, const float* __restrict__ s2,
    unsigned short* __restrict__ d1, unsigned short* __restrict__ d2)
{
  int idx = blockIdx.x * 256 + threadIdx.x;
  d1[idx] = f2bf(s1[idx]);
  d2[idx] = f2bf(s2[idx]);
}

// ---- fused multi-scale depthwise conv -> bf16 [c][n], both streams ---------
// One block per (stream,b,c) plane. Row-shifted LDS layout: base(row) =
// 84*row + 8*((row>>3)&1) -> wave's 4 rows hit banks {0,8,16,24}, 2-way max.
__global__ __launch_bounds__(256) void ms_conv(
    const float* __restrict__ x1, const float* __restrict__ x2,
    const float* __restrict__ weff, const float* __restrict__ beff,
    unsigned short* __restrict__ xf0, unsigned short* __restrict__ xf1)
{
  __shared__ float tile[5888];
  const int bc2 = blockIdx.x;                   // [stream][b][c]
  const int s = bc2 >> 11, bc = bc2 & 2047;
  const int c = bc & 255;
  const int tid = threadIdx.x;
  const float* src = (s ? x2 : x1) + (size_t)bc * NPIX;
  float wreg[49];
#pragma unroll
  for (int i = 0; i < 49; ++i) wreg[i] = weff[c * 49 + i];
  const float bias = beff[c];
  // ---- stage interior: 64 rows x 16 quads, linear global read -------------
  float4 vv[4];
#pragma unroll
  for (int k = 0; k < 4; ++k)
    vv[k] = *(const float4*)&src[(k * 256 + tid) * 4];
#pragma unroll
  for (int k = 0; k < 4; ++k) {
    const int idx = k * 256 + tid;
    const int row = (idx >> 4) + 3;           // tile rows 3..66
    const int col = 4 + (idx & 15) * 4;       // tile cols 4..67
    *(float4*)&tile[84 * row + ((row >> 3) & 1) * 8 + col] = vv[k];
  }
  // ---- zero pads ----------------------------------------------------------
  const float4 zq = {0.0f, 0.0f, 0.0f, 0.0f};
  for (int idx = tid; idx < 306; idx += 256) {
    int row, col;
    if (idx < 114) {
      int r6 = idx / 19;
      col = (idx - r6 * 19) * 4;
      row = (r6 < 3) ? r6 : (r6 + 64);        // rows 0..2, 67..69
    } else {
      int j = idx - 114;
      int r64 = j / 3, q = j - r64 * 3;
      row = 3 + r64;                           // rows 3..66
      col = (q == 0) ? 0 : (64 + q * 4);       // cols 0, 68, 72
    }
    *(float4*)&tile[84 * row + ((row >> 3) & 1) * 8 + col] = zq;
  }
  __syncthreads();
  // ---- compute: 4x4 outputs per thread ------------------------------------
  const int x0 = (tid & 15) * 4;
  const int y0 = (tid >> 4) * 4;
  float acc[4][4];
#pragma unroll
  for (int yo = 0; yo < 4; ++yo)
#pragma unroll
    for (int xo = 0; xo < 4; ++xo) acc[yo][xo] = bias;
#pragma unroll
  for (int r = 0; r < 10; ++r) {
    const int row = y0 + r;
    const int rb = 84 * row + ((row >> 3) & 1) * 8 + x0;
    float seg[12];
    *(float4*)&seg[0] = *(const float4*)&tile[rb];
    *(float4*)&seg[4] = *(const float4*)&tile[rb + 4];
    *(float4*)&seg[8] = *(const float4*)&tile[rb + 8];
    const int yolo = (r >= 6) ? (r - 6) : 0;
    const int yohi = (r < 3) ? r : 3;
#pragma unroll
    for (int yo = 0; yo < 4; ++yo) {
      if (yo < yolo || yo > yohi) continue;
      const int ky = r - yo;
#pragma unroll
      for (int kx = 0; kx < 7; ++kx) {
        const float w = wreg[ky * 7 + kx];
#pragma unroll
        for (int xo = 0; xo < 4; ++xo)
          acc[yo][xo] = fmaf(w, seg[1 + xo + kx], acc[yo][xo]);
      }
    }
  }
  unsigned short* dst = (s ? xf1 : xf0) + (size_t)bc * NPIX;
#pragma unroll
  for (int yo = 0; yo < 4; ++yo) {
    ushort4 u;
    u.x = f2bf(acc[yo][0]); u.y = f2bf(acc[yo][1]);
    u.z = f2bf(acc[yo][2]); u.w = f2bf(acc[yo][3]);
    *(ushort4*)&dst[(y0 + yo) * 64 + x0] = u;
  }
}

// ---- bf16 [R rows][4096] -> [4096][256] tile transpose, both streams -------
__global__ __launch_bounds__(256) void transpose_bf16(
    const unsigned short* __restrict__ s0, unsigned short* __restrict__ d0,
    const unsigned short* __restrict__ s1, unsigned short* __restrict__ d1,
    long sb, long db)
{
  __shared__ unsigned short T[64][72];
  const int n0 = blockIdx.x * 64, c0 = blockIdx.y * 64;
  const int z = blockIdx.z, st = z >> 3, b = z & 7;
  const unsigned short* src = st ? s1 : s0;
  unsigned short* dst = st ? d1 : d0;
  const int t = threadIdx.x;
  const int rhi = t >> 4, c4 = (t & 15) * 4;
#pragma unroll
  for (int rr = 0; rr < 4; ++rr) {
    int row = rr * 16 + rhi;
    ushort4 u = *(const ushort4*)&src[(size_t)b * sb + (size_t)(c0 + row) * NPIX + n0 + c4];
    T[row][c4 + 0] = u.x; T[row][c4 + 1] = u.y;
    T[row][c4 + 2] = u.z; T[row][c4 + 3] = u.w;
  }
  __syncthreads();
#pragma unroll
  for (int rr = 0; rr < 4; ++rr) {
    int nrow = rr * 16 + rhi;
    ushort4 u;
    u.x = T[c4 + 0][nrow]; u.y = T[c4 + 1][nrow];
    u.z = T[c4 + 2][nrow]; u.w = T[c4 + 3][nrow];
    *(ushort4*)&dst[(size_t)b * db + (size_t)(n0 + nrow) * 256 + c0 + c4] = u;
  }
}

// ---- qkv 1x1 GEMM (MFMA), single 32KB LDS buffer, 2-barrier loop -----------
// D[n][o], A=Xt(n rows), B=W(o rows). LDS swizzle: slot g -> g ^ (row & 7).
// q/k blocks (o0<512): BN+gelu -> qkv[o][n] + fused row-sumsq atomics.
// v blocks (o0>=512): BN+gelu -> 128x128 LDS transpose (XOR swizzle
//   idx = (n*128+o) ^ (((n>>2)&7)<<3)) -> coalesced vt[n][c] stores.
__global__ __launch_bounds__(256) void qkv_gemm(
    const unsigned short* __restrict__ W1, const unsigned short* __restrict__ W2,
    const unsigned short* __restrict__ X0, const unsigned short* __restrict__ X1,
    const float* __restrict__ alpha, const float* __restrict__ beta,
    unsigned short* __restrict__ q1, unsigned short* __restrict__ q2,
    float* __restrict__ ns,
    unsigned short* __restrict__ v1t, unsigned short* __restrict__ v2t)
{
  __shared__ unsigned short smem[16384];   // 32KB: As | Bs, reused as T
  unsigned short* As = smem;               // W tile (o rows), 128x64
  unsigned short* Bs = smem + 8192;        // Xt tile (n rows), 128x64
  const int n0 = blockIdx.x * 128, o0 = blockIdx.y * 128;
  const int z = blockIdx.z, s = z >> 3, b = z & 7;
  const unsigned short* Wb = s ? W2 : W1;
  const unsigned short* Xt = s ? X1 : X0;
  unsigned short* qkv = s ? q2 : q1;
  const float* al = alpha + s * 768;
  const float* be = beta + s * 768;
  float* normsq = ns + s * 4096;
  const bool vsw = (o0 >= 512);
  const int tid = threadIdx.x, w = tid >> 6, lane = tid & 63;
  const int wm = (w & 1) * 64;   // n wave offset
  const int wn = (w >> 1) * 64;  // o wave offset
  const int lrow8 = lane >> 3;
  const int lcolsw = ((lane & 7) ^ lrow8) * 8;  // swizzled source column
  const int fslot = lane & 7;                    // read-side row&7
  f4acc acc[4][4] = {};
  auto stage = [&](int kc) {
#pragma unroll
    for (int j = 0; j < 4; ++j) {
      int i = w * 4 + j;
      GLDS16(Wb + (size_t)(o0 + i * 8 + lrow8) * 256 + kc + lcolsw, &As[i * 512]);
      GLDS16(Xt + (size_t)b * 1048576 + (size_t)(n0 + i * 8 + lrow8) * 256 + kc + lcolsw,
             &Bs[i * 512]);
    }
  };
  stage(0);
#pragma unroll
  for (int t = 0; t < 4; ++t) {
    __syncthreads();   // own vmcnt drained + stage visible to block
#pragma unroll
    for (int ks = 0; ks < 2; ++ks) {
      const int slot = ((ks * 4 + (lane >> 4)) ^ fslot) * 8;
      bfrag a[4], bb[4];
#pragma unroll
      for (int mt = 0; mt < 4; ++mt)   // A = Xt rows (n)
        a[mt] = *(const bfrag*)&Bs[(wm + mt * 16 + (lane & 15)) * 64 + slot];
#pragma unroll
      for (int nt = 0; nt < 4; ++nt)   // B = W rows (o)
        bb[nt] = *(const bfrag*)&As[(wn + nt * 16 + (lane & 15)) * 64 + slot];
#pragma unroll
      for (int mt = 0; mt < 4; ++mt)
#pragma unroll
        for (int nt = 0; nt < 4; ++nt)
          acc[mt][nt] = __builtin_amdgcn_mfma_f32_16x16x32_bf16(a[mt], bb[nt], acc[mt][nt], 0, 0, 0);
    }
    if (t < 3) {
      __syncthreads();   // all reads of this tile done before overwrite
      stage((t + 1) * 64);
    }
  }
  if (!vsw) {
    // epilogue: D rows = n (regs), cols = o (lane&15)
#pragma unroll
    for (int nt = 0; nt < 4; ++nt) {
      const int o = o0 + wn + nt * 16 + (lane & 15);
      const float alv = al[o], bev = be[o];
      unsigned short* orow = qkv + ((size_t)b * 768 + o) * NPIX;
      float sq = 0.0f;
#pragma unroll
      for (int mt = 0; mt < 4; ++mt) {
        const int n = n0 + wm + mt * 16 + (lane >> 4) * 4;
        float v0 = gelu_f(acc[mt][nt][0] * alv + bev);
        float v1 = gelu_f(acc[mt][nt][1] * alv + bev);
        float v2 = gelu_f(acc[mt][nt][2] * alv + bev);
        float v3 = gelu_f(acc[mt][nt][3] * alv + bev);
        ushort4 u;
        u.x = f2bf(v0); u.y = f2bf(v1); u.z = f2bf(v2); u.w = f2bf(v3);
        *(ushort4*)&orow[n] = u;
        sq += v0 * v0 + v1 * v1 + v2 * v2 + v3 * v3;
      }
      sq += __shfl_xor(sq, 16);
      sq += __shfl_xor(sq, 32);
      if (lane < 16) atomicAdd(&normsq[b * 512 + o], sq);
    }
  } else {
    // v blocks: BN+gelu, transpose 128x128 tile through LDS, store vt[n][c]
    __syncthreads();   // all MFMA reads of smem complete
#pragma unroll
    for (int nt = 0; nt < 4; ++nt) {
      const int o = o0 + wn + nt * 16 + (lane & 15);
      const float alv = al[o], bev = be[o];
      const int ol = wn + nt * 16 + (lane & 15);
#pragma unroll
      for (int mt = 0; mt < 4; ++mt) {
        const int nb = wm + mt * 16 + (lane >> 4) * 4;
#pragma unroll
        for (int j = 0; j < 4; ++j) {
          const int nl = nb + j;
          smem[(nl * 128 + ol) ^ (((nl >> 2) & 7) << 3)] =
              f2bf(gelu_f(acc[mt][nt][j] * alv + bev));
        }
      }
    }
    __syncthreads();
    unsigned short* vtb = (s ? v2t : v1t) + (size_t)b * 1048576;
    const int row = tid & 127;
    const int cg = (tid >> 7) * 8;   // 8 chunks of 8 ushorts each
    const int c0 = o0 - 512;
#pragma unroll
    for (int ch = 0; ch < 8; ++ch) {
      const int chunk = cg + ch;
      const int idx = (row * 128 + chunk * 8) ^ (((row >> 2) & 7) << 3);
      float4 v4 = *(const float4*)&smem[idx];
      *(float4*)&vtb[(size_t)(n0 + row) * 256 + c0 + chunk * 8] = v4;
    }
  }
}

// ---- spart (MFMA), both streams, 2-phase dbuf pipeline (R7 form) -----------
// Sp[c][d] += sum_n q[c][n]*k[d][n]; A=k(d), B=q(c).
// grid (8 chunks of 512 n, 4 h, 16 = stream*8+b). 128-el rows, swizzle &15.
__global__ __launch_bounds__(256) void spart_kernel(
    const unsigned short* __restrict__ qkv1, const unsigned short* __restrict__ qkv2,
    float* __restrict__ Sp0, float* __restrict__ Sp1)
{
  __shared__ unsigned short Qs[2][64 * 128];
  __shared__ unsigned short Ks[2][64 * 128];
  const int ck = blockIdx.x, h = blockIdx.y;
  const int z = blockIdx.z, s = z >> 3, b = z & 7;
  const unsigned short* qs = s ? qkv2 : qkv1;
  const unsigned short* kp = (s ? qkv1 : qkv2) + 256 * NPIX;
  float* Sp = s ? Sp1 : Sp0;
  const int tid = threadIdx.x, w = tid >> 6, lane = tid & 63;
  const int lrow16 = lane >> 4;
  const size_t qbase = ((size_t)b * 768 + h * 64) * NPIX;
  f4acc acc[4] = {};   // mt over d tiles
  auto stage = [&](int buf, int it) {
    const int noff = ck * 512 + it * 128;
#pragma unroll
    for (int j = 0; j < 4; ++j) {
      int i = w * 4 + j;
      int row = i * 4 + lrow16;
      int colsw = ((lane & 15) ^ (row & 15)) * 8;
      GLDS16(qs + qbase + (size_t)row * NPIX + noff + colsw, &Qs[buf][i * 512]);
      GLDS16(kp + qbase + (size_t)row * NPIX + noff + colsw, &Ks[buf][i * 512]);
    }
  };
  stage(0, 0);
#pragma unroll
  for (int it = 0; it < 4; ++it) {
    const int cur = it & 1;
    if (it < 3) stage(cur ^ 1, it + 1);
    if (it < 3) asm volatile("s_waitcnt vmcnt(8)" ::: "memory");
    else        asm volatile("s_waitcnt vmcnt(0)" ::: "memory");
    __builtin_amdgcn_s_barrier();
#pragma unroll
    for (int kk = 0; kk < 4; ++kk) {
      const int slot = ((kk * 4 + (lane >> 4)) ^ (lane & 15)) * 8;
      bfrag bq = *(const bfrag*)&Qs[cur][(w * 16 + (lane & 15)) * 128 + slot];  // B = q (c)
#pragma unroll
      for (int mt = 0; mt < 4; ++mt) {
        bfrag ak = *(const bfrag*)&Ks[cur][(mt * 16 + (lane & 15)) * 128 + slot];  // A = k (d)
        acc[mt] = __builtin_amdgcn_mfma_f32_16x16x32_bf16(ak, bq, acc[mt], 0, 0, 0);
      }
    }
    __builtin_amdgcn_s_barrier();
  }
  // D rows = d (regs), cols = c (lane&15); c covered by wave w: w*16..+15
  float* dst = Sp + ((size_t)(ck * 32) + b * 4 + h) * 4096;
  const int c = w * 16 + (lane & 15);
#pragma unroll
  for (int mt = 0; mt < 4; ++mt)
    *(float4*)&dst[c * 64 + mt * 16 + (lane >> 4) * 4] = *(float4*)&acc[mt];
}

// ---- reduce partials, scale by inv norms * temp, softmax, write bf16 -------
__global__ __launch_bounds__(256) void softattn(
    const float* __restrict__ Sp0, const float* __restrict__ Sp1,
    const float* __restrict__ ns,
    unsigned short* __restrict__ at0, unsigned short* __restrict__ at1)
{
  const int bh2 = blockIdx.x;            // [stream][b][h]
  const int s = bh2 >> 5, bh = bh2 & 31;
  const int b = bh >> 2, h = bh & 3;
  const float* Sp = s ? Sp1 : Sp0;
  const float* nsq = ns + s * 4096;
  const float* nsk = ns + (s ^ 1) * 4096;
  unsigned short* attn = s ? at1 : at0;
  const int wv = threadIdx.x >> 6, lane = threadIdx.x & 63;
  const float ikd = 1.0f / fmaxf(sqrtf(nsk[b * 512 + 256 + h * 64 + lane]), 1e-12f);
  for (int c = wv; c < 64; c += 4) {
    float sm = 0.0f;
#pragma unroll
    for (int ch = 0; ch < 8; ++ch)
      sm += Sp[((size_t)(ch * 32) + bh) * 4096 + c * 64 + lane];
    const float iq = 1.0f / fmaxf(sqrtf(nsq[b * 512 + h * 64 + c]), 1e-12f);
    float zv = sm * 0.125f * iq * ikd;
    float m = zv;
#pragma unroll
    for (int off = 32; off > 0; off >>= 1) m = fmaxf(m, __shfl_xor(m, off));
    float e = expf(zv - m);
    float sum = e;
#pragma unroll
    for (int off = 32; off > 0; off >>= 1) sum += __shfl_xor(sum, off);
    attn[(size_t)bh * 4096 + c * 64 + lane] = f2bf(e / sum);
  }
}

// ---- av (MFMA), both streams: xout_t[n'][c] = sum_d attn[c][d]*v_t[n'][d] --
// A = attn (c rows), B = vt (n' rows) -> regs = 4 consecutive c at fixed n'.
// grid (16 chunks of 256 n', 4 h, 16 = stream*8+b).
__global__ __launch_bounds__(256) void av_kernel(
    const unsigned short* __restrict__ vt0, const unsigned short* __restrict__ vt1,
    const unsigned short* __restrict__ at0, const unsigned short* __restrict__ at1,
    unsigned short* __restrict__ xo0, unsigned short* __restrict__ xo1,
    long db, float* __restrict__ pool)
{
  __shared__ unsigned short Vs[256 * 64];
  __shared__ unsigned short At[64 * 64];
  const int n0 = blockIdx.x * 256, h = blockIdx.y;
  const int z = blockIdx.z, s = z >> 3, b = z & 7;
  const unsigned short* vt = s ? vt1 : vt0;
  const unsigned short* attn = s ? at1 : at0;
  unsigned short* xout = s ? xo1 : xo0;
  float* pl = pool + s * 2048;
  const int tid = threadIdx.x, w = tid >> 6, lane = tid & 63;
  const int lrow8 = lane >> 3;
  const int lcolsw = ((lane & 7) ^ lrow8) * 8;
  const int bh = b * 4 + h;
#pragma unroll
  for (int j = 0; j < 8; ++j) {
    int i = w * 8 + j;
    GLDS16(vt + ((size_t)b * 1048576 + (size_t)(n0 + i * 8 + lrow8) * 256) + h * 64 + lcolsw,
           &Vs[i * 512]);
  }
#pragma unroll
  for (int j = 0; j < 2; ++j) {
    int i = w * 2 + j;
    GLDS16(attn + (size_t)bh * 4096 + (size_t)(i * 8 + lrow8) * 64 + lcolsw, &At[i * 512]);
  }
  __syncthreads();
  f4acc acc[4][4] = {};   // [mt = c tile][nt = n' tile]
#pragma unroll
  for (int ks = 0; ks < 2; ++ks) {
    const int slot = ((ks * 4 + (lane >> 4)) ^ (lane & 7)) * 8;
    bfrag a[4], bb[4];
#pragma unroll
    for (int mt = 0; mt < 4; ++mt)    // A = attn rows (c)
      a[mt] = *(const bfrag*)&At[(mt * 16 + (lane & 15)) * 64 + slot];
#pragma unroll
    for (int nt = 0; nt < 4; ++nt)    // B = vt rows (n')
      bb[nt] = *(const bfrag*)&Vs[(w * 64 + nt * 16 + (lane & 15)) * 64 + slot];
#pragma unroll
    for (int mt = 0; mt < 4; ++mt)
#pragma unroll
      for (int nt = 0; nt < 4; ++nt)
        acc[mt][nt] = __builtin_amdgcn_mfma_f32_16x16x32_bf16(a[mt], bb[nt], acc[mt][nt], 0, 0, 0);
  }
  // D rows = c (regs), cols = n' (lane&15)
#pragma unroll
  for (int mt = 0; mt < 4; ++mt) {
    const int c = mt * 16 + (lane >> 4) * 4;
    float s0 = 0.0f, s1 = 0.0f, s2 = 0.0f, s3 = 0.0f;
#pragma unroll
    for (int nt = 0; nt < 4; ++nt) {
      const int np = n0 + w * 64 + nt * 16 + (lane & 15);
      ushort4 u;
      u.x = f2bf(acc[mt][nt][0]); u.y = f2bf(acc[mt][nt][1]);
      u.z = f2bf(acc[mt][nt][2]); u.w = f2bf(acc[mt][nt][3]);
      *(ushort4*)&xout[(size_t)b * db + (size_t)np * 256 + h * 64 + c] = u;
      s0 += acc[mt][nt][0]; s1 += acc[mt][nt][1];
      s2 += acc[mt][nt][2]; s3 += acc[mt][nt][3];
    }
    // reduce over n' (lane&15) for fixed c
    s0 += __shfl_xor(s0, 1); s0 += __shfl_xor(s0, 2); s0 += __shfl_xor(s0, 4); s0 += __shfl_xor(s0, 8);
    s1 += __shfl_xor(s1, 1); s1 += __shfl_xor(s1, 2); s1 += __shfl_xor(s1, 4); s1 += __shfl_xor(s1, 8);
    s2 += __shfl_xor(s2, 1); s2 += __shfl_xor(s2, 2); s2 += __shfl_xor(s2, 4); s2 += __shfl_xor(s2, 8);
    s3 += __shfl_xor(s3, 1); s3 += __shfl_xor(s3, 2); s3 += __shfl_xor(s3, 4); s3 += __shfl_xor(s3, 8);
    if ((lane & 15) == 0) {
      atomicAdd(&pl[b * 256 + h * 64 + c + 0], s0);
      atomicAdd(&pl[b * 256 + h * 64 + c + 1], s1);
      atomicAdd(&pl[b * 256 + h * 64 + c + 2], s2);
      atomicAdd(&pl[b * 256 + h * 64 + c + 3], s3);
    }
  }
}

// ---- SE gate MLP + fold gate into per-batch bf16 output-proj weights -------
__global__ __launch_bounds__(256) void segate_scale(
    const float* __restrict__ pool, const float* __restrict__ w1,
    const float* __restrict__ b1, const float* __restrict__ w2,
    const float* __restrict__ b2,
    const float* __restrict__ W1, const float* __restrict__ W2,
    unsigned short* __restrict__ Wg)
{
  const int b16 = blockIdx.x;   // [stream][b]
  const int tid = threadIdx.x;
  __shared__ float p[256];
  __shared__ float hh[32];
  p[tid] = pool[b16 * 256 + tid] * (1.0f / 4096.0f);
  __syncthreads();
  if (tid < 32) {
    float s = b1[tid];
    for (int c = 0; c < 256; ++c) s = fmaf(w1[tid * 256 + c], p[c], s);
    hh[tid] = fmaxf(s, 0.0f);
  }
  __syncthreads();
  float s = b2[tid];
#pragma unroll
  for (int r = 0; r < 32; ++r) s = fmaf(w2[tid * 32 + r], hh[r], s);
  const float g = 1.0f / (1.0f + expf(-s));
  const float* W = (b16 >> 3) ? W2 : W1;
  for (int o = 0; o < 256; ++o)
    Wg[(size_t)b16 * 65536 + o * 256 + tid] = f2bf(W[o * 256 + tid] * g);
}

// ---- pout (MFMA), both streams, 2-phase dbuf pipeline (R7 form) ------------
// out[o][n] = sum_c Wg[o][c]*xout_t[n][c] + bias + res.
__global__ __launch_bounds__(256) void pout_gemm(
    const unsigned short* __restrict__ Wgall,
    const unsigned short* __restrict__ X0, const unsigned short* __restrict__ X1,
    long db, const float* __restrict__ bias0, const float* __restrict__ bias1,
    const float* __restrict__ xr0, const float* __restrict__ xr1,
    float* __restrict__ out)
{
  __shared__ unsigned short As[2][128 * 64];  // Wg (o rows)
  __shared__ unsigned short Bs[2][128 * 64];  // Xt (n rows)
  const int n0 = blockIdx.x * 128, o0 = blockIdx.y * 128;
  const int z = blockIdx.z, s = z >> 3, b = z & 7;
  const unsigned short* Wg = Wgall + (size_t)z * 65536;
  const unsigned short* Xt = s ? X1 : X0;
  const float* bias = s ? bias1 : bias0;
  const float* xresb = s ? xr1 : xr0;
  float* outb = out + (size_t)s * 8388608;
  const int tid = threadIdx.x, w = tid >> 6, lane = tid & 63;
  const int wm = (w & 1) * 64;   // n
  const int wn = (w >> 1) * 64;  // o
  const int lrow8 = lane >> 3;
  const int lcolsw = ((lane & 7) ^ lrow8) * 8;
  const int fslot = lane & 7;
  f4acc acc[4][4] = {};
  auto stage = [&](int buf, int kc) {
#pragma unroll
    for (int j = 0; j < 4; ++j) {
      int i = w * 4 + j;
      GLDS16(Wg + (size_t)(o0 + i * 8 + lrow8) * 256 + kc + lcolsw, &As[buf][i * 512]);
      GLDS16(Xt + (size_t)b * db + (size_t)(n0 + i * 8 + lrow8) * 256 + kc + lcolsw,
             &Bs[buf][i * 512]);
    }
  };
  stage(0, 0);
#pragma unroll
  for (int t = 0; t < 4; ++t) {
    const int cur = t & 1;
    if (t < 3) stage(cur ^ 1, (t + 1) * 64);
    if (t < 3) asm volatile("s_waitcnt vmcnt(8)" ::: "memory");
    else       asm volatile("s_waitcnt vmcnt(0)" ::: "memory");
    __builtin_amdgcn_s_barrier();
#pragma unroll
    for (int ks = 0; ks < 2; ++ks) {
      const int slot = ((ks * 4 + (lane >> 4)) ^ fslot) * 8;
      bfrag a[4], bb[4];
#pragma unroll
      for (int mt = 0; mt < 4; ++mt)   // A = Xt rows (n)
        a[mt] = *(const bfrag*)&Bs[cur][(wm + mt * 16 + (lane & 15)) * 64 + slot];
#pragma unroll
      for (int nt = 0; nt < 4; ++nt)   // B = Wg rows (o)
        bb[nt] = *(const bfrag*)&As[cur][(wn + nt * 16 + (lane & 15)) * 64 + slot];
#pragma unroll
      for (int mt = 0; mt < 4; ++mt)
#pragma unroll
        for (int nt = 0; nt < 4; ++nt)
          acc[mt][nt] = __builtin_amdgcn_mfma_f32_16x16x32_bf16(a[mt], bb[nt], acc[mt][nt], 0, 0, 0);
    }
    __builtin_amdgcn_s_barrier();
  }
#pragma unroll
  for (int nt = 0; nt < 4; ++nt) {
    const int o = o0 + wn + nt * 16 + (lane & 15);
    const float bi = bias[o];
    const float* res = xresb + ((size_t)b * 256 + o) * NPIX;
    float* orow = outb + ((size_t)b * 256 + o) * NPIX;
#pragma unroll
    for (int mt = 0; mt < 4; ++mt) {
      const int n = n0 + wm + mt * 16 + (lane >> 4) * 4;
      float4 r4 = *(const float4*)&res[n];
      float4 ov;
      ov.x = acc[mt][nt][0] + bi + r4.x;
      ov.y = acc[mt][nt][1] + bi + r4.y;
      ov.z = acc[mt][nt][2] + bi + r4.z;
      ov.w = acc[mt][nt][3] + bi + r4.w;
      *(float4*)&orow[n] = ov;
    }
  }
}

extern "C" void kernel_launch(void* const* d_in, const int* in_sizes, int n_in,
                              void* d_out, int out_size, void* d_ws, size_t ws_size,
                              hipStream_t stream) {
  const float* x1    = (const float*)d_in[0];
  const float* x2    = (const float*)d_in[1];
  const float* ms_w3 = (const float*)d_in[2];
  const float* ms_b3 = (const float*)d_in[3];
  const float* ms_w5 = (const float*)d_in[4];
  const float* ms_b5 = (const float*)d_in[5];
  const float* ms_w7 = (const float*)d_in[6];
  const float* ms_b7 = (const float*)d_in[7];
  const float* qkv1_w = (const float*)d_in[8];
  const float* qkv1_b = (const float*)d_in[9];
  const float* bn1_g = (const float*)d_in[10];
  const float* bn1_b = (const float*)d_in[11];
  const float* bn1_m = (const float*)d_in[12];
  const float* bn1_v = (const float*)d_in[13];
  const float* qkv2_w = (const float*)d_in[14];
  const float* qkv2_b = (const float*)d_in[15];
  const float* bn2_g = (const float*)d_in[16];
  const float* bn2_b = (const float*)d_in[17];
  const float* bn2_m = (const float*)d_in[18];
  const float* bn2_v = (const float*)d_in[19];
  const float* ca_w1 = (const float*)d_in[20];
  const float* ca_b1 = (const float*)d_in[21];
  const float* ca_w2 = (const float*)d_in[22];
  const float* ca_b2 = (const float*)d_in[23];
  const float* po1_w = (const float*)d_in[24];
  const float* po1_b = (const float*)d_in[25];
  const float* po2_w = (const float*)d_in[26];
  const float* po2_b = (const float*)d_in[27];

  char* ws = (char*)d_ws;
  float* weff  = (float*)(ws + 0);
  float* beff  = (float*)(ws + 51200);
  float* alpha = (float*)(ws + 53248);
  float* beta  = (float*)(ws + 59392);
  float* normsq = (float*)(ws + 65536);    // 2 streams x 8*512 fp32
  float* pool  = (float*)(ws + 98304);     // 2 streams x 2048 fp32
  unsigned short* W1b = (unsigned short*)(ws + 131072);
  unsigned short* W2b = (unsigned short*)(ws + 524288);
  unsigned short* Wg  = (unsigned short*)(ws + 917504);   // 16 x 65536 bf16
  unsigned short* attn1 = (unsigned short*)(ws + 3014656);
  unsigned short* attn2 = (unsigned short*)(ws + 3276800);
  float* Sp    = (float*)(ws + 3538944);   // stream1 partials, 4.2 MB
  unsigned short* xf   = (unsigned short*)(ws + 7733248);   // [b][256][4096]
  unsigned short* xf_t = (unsigned short*)(ws + 24510464);  // [b][4096][256]
  unsigned short* qkv1 = (unsigned short*)(ws + 41287680);  // [b][768][4096]
  unsigned short* qkv2 = (unsigned short*)(ws + 91619328);
  // d_out scratch (everything dead before pout_gemm writes outf):
  unsigned short* xf2   = (unsigned short*)d_out;                        // 0..16.8M
  unsigned short* xf2_t = (unsigned short*)((char*)d_out + 16777216);    // 16.8..33.6M
  unsigned short* v2t   = (unsigned short*)((char*)d_out + 33554432);    // 33.6..50.3M
  unsigned short* v1t   = (unsigned short*)((char*)d_out + 50331648);    // 50.3..67.1M
  // stream-2 score partials live in the (dead at that point) xf region
  float* Sp2 = (float*)(ws + 7733248);
  unsigned short* xout1 = qkv2;   // per-batch [n][256] in dead q/k chunks
  unsigned short* xout2 = qkv1;
  const long QKV_BSTR = 768L * 4096;

  float* outf = (float*)d_out;

  prep_kernel<<<1, 256, 0, stream>>>(ms_w3, ms_b3, ms_w5, ms_b5, ms_w7, ms_b7,
                                     qkv1_b, bn1_g, bn1_b, bn1_m, bn1_v,
                                     qkv2_b, bn2_g, bn2_b, bn2_m, bn2_v,
                                     weff, beff, alpha, beta);
  convert_w<<<768, 256, 0, stream>>>(qkv1_w, qkv2_w, W1b, W2b);
  hipMemsetAsync(ws + 65536, 0, 49152, stream);  // normsq(both) + pool(both)

  ms_conv<<<4096, 256, 0, stream>>>(x1, x2, weff, beff, xf, xf2);
  transpose_bf16<<<dim3(64, 4, 16), 256, 0, stream>>>(xf, xf_t, xf2, xf2_t,
                                                      1048576L, 1048576L);
  qkv_gemm<<<dim3(32, 6, 16), 256, 0, stream>>>(W1b, W2b, xf_t, xf2_t,
                                                alpha, beta, qkv1, qkv2, normsq,
                                                v1t, v2t);

  spart_kernel<<<dim3(8, 4, 16), 256, 0, stream>>>(qkv1, qkv2, Sp, Sp2);
  softattn<<<64, 256, 0, stream>>>(Sp, Sp2, normsq, attn1, attn2);

  av_kernel<<<dim3(16, 4, 16), 256, 0, stream>>>(v1t, v2t, attn1, attn2,
                                                 xout1, xout2, QKV_BSTR, pool);

  segate_scale<<<16, 256, 0, stream>>>(pool, ca_w1, ca_b1, ca_w2, ca_b2,
                                       po1_w, po2_w, Wg);

  pout_gemm<<<dim3(32, 2, 16), 256, 0, stream>>>(Wg, xout1, xout2, QKV_BSTR,
                                                 po1_b, po2_b, x1, x2, outf);
}